// Round 2
// baseline (32851.779 us; speedup 1.0000x reference)
//
#include <hip/hip_runtime.h>
#include <cstdint>
#include <cstddef>

#define BB 64
#define TT 2048
#define DD 128
#define HH 256
#define G4 1024              // 4*H

typedef _Float16 half4_t __attribute__((ext_vector_type(4)));
typedef _Float16 half8_t __attribute__((ext_vector_type(8)));
typedef float floatx4 __attribute__((ext_vector_type(4)));
typedef float floatx2 __attribute__((ext_vector_type(2)));

__device__ __forceinline__ float sigm(float x) { return 1.f / (1.f + __expf(-x)); }
__device__ __forceinline__ float tanh_f(float x) { return 1.f - 2.f / (1.f + __expf(2.f * x)); }

// ---------------- prep: K^T fp16: kT[dir][n][k] = K[dir][k][n] ----------------

__global__ void cvt_w_kernel(const float* __restrict__ kf, const float* __restrict__ kb,
                             _Float16* __restrict__ kT) {
  int idx = blockIdx.x * 256 + threadIdx.x;  // 0..262143
  int dir = idx >> 17;
  int r = idx & 131071;
  int n = r >> 7, kk = r & 127;
  const float* src = dir ? kb : kf;
  kT[idx] = (_Float16)src[kk * G4 + n];
}

// ---------------- fused recurrence ----------------
// 64 blocks = 2 dirs x 32 batch-pairs, 512 threads (8 waves) = 1 block/CU.
// Per step:
//   xproj (MFMA, idle matrix pipe): z_lds[batch][col] = x_t @ K  (fp16 MFMA)
//   h@R (fp32 VALU): z += h_{t-1} @ R   (R streamed from L2, 1 MB/step/block)
//   gates: c,h update; h -> LDS + deferred fp16 global store.
// K^T B-fragments are loop-invariant -> 128 persistent VGPRs.

__device__ __forceinline__ void load_a(const float* xb, int tx, int q, bool av,
                                       half8_t a[4]) {
#pragma unroll
  for (int ks = 0; ks < 4; ++ks) {
    half8_t v{};
    if (av) {
      const float* p = xb + (size_t)tx * DD + ks * 32 + q * 8;
      float4 u0 = *reinterpret_cast<const float4*>(p);
      float4 u1 = *reinterpret_cast<const float4*>(p + 4);
      v[0] = (_Float16)u0.x; v[1] = (_Float16)u0.y;
      v[2] = (_Float16)u0.z; v[3] = (_Float16)u0.w;
      v[4] = (_Float16)u1.x; v[5] = (_Float16)u1.y;
      v[6] = (_Float16)u1.z; v[7] = (_Float16)u1.w;
    }
    a[ks] = v;
  }
}

__global__ __launch_bounds__(512, 2) void lstm_rec_kernel(
    const float* __restrict__ x,
    const float* __restrict__ rec_f, const float* __restrict__ rec_b,
    const float* __restrict__ bias_f, const float* __restrict__ bias_b,
    const _Float16* __restrict__ kT,
    _Float16* __restrict__ hseq) {
  const int bid = blockIdx.x;       // 0..63
  const int dir = bid >> 5;
  const int b0 = (bid & 31) * 2;
  const float* __restrict__ rec = dir ? rec_b : rec_f;
  const float* __restrict__ bias = dir ? bias_b : bias_f;
  const int tid = threadIdx.x;
  const int w = tid >> 6, lane = tid & 63;
  const int lo16 = lane & 15, q = lane >> 4;
  const int half_id = tid >> 8;     // z-phase: col half; gate-phase: batch
  const int l = tid & 255;
  const int col0 = half_id * 512 + l * 2;

  __shared__ float h_lds[HH * 2];   // [k][batch] packed float2
  __shared__ float z_lds[2][G4];    // [batch][col]

  // persistent B-fragments of K^T: wave w owns cols [w*128, (w+1)*128)
  half8_t bfr[8][4];
  {
    const _Float16* kTd = kT + (size_t)dir * (G4 * DD);
#pragma unroll
    for (int j = 0; j < 8; ++j) {
      const _Float16* bp = kTd + (size_t)(w * 128 + j * 16 + lo16) * DD + q * 8;
#pragma unroll
      for (int ks = 0; ks < 4; ++ks)
        bfr[j][ks] = *reinterpret_cast<const half8_t*>(bp + ks * 32);
    }
  }

  const float bi = bias[l], bf = bias[256 + l], bg = bias[512 + l], bo = bias[768 + l];

  for (int i = tid; i < HH * 2; i += 512) h_lds[i] = 0.f;

  const bool av = (lo16 < 2);
  const float* xb = x + (size_t)(b0 + (av ? lo16 : 0)) * TT * DD;

  float c_state = 0.f, h_prev = 0.f;
  int tx_prev = 0;
  _Float16* hsp = hseq + ((size_t)(dir * BB + b0 + half_id)) * TT * HH + l;

  half8_t afr[4];
  load_a(xb, dir ? TT - 1 : 0, q, av, afr);
  __syncthreads();

  for (int s = 0; s < TT; ++s) {
    const int tx = dir ? (TT - 1 - s) : s;

    // ---- xproj via MFMA: rows 0,1 of the 16x16 tile are batches b0, b0+1 ----
#pragma unroll
    for (int j = 0; j < 8; ++j) {
      floatx4 acc = {0.f, 0.f, 0.f, 0.f};
#pragma unroll
      for (int ks = 0; ks < 4; ++ks)
        acc = __builtin_amdgcn_mfma_f32_16x16x32_f16(afr[ks], bfr[j][ks], acc, 0, 0, 0);
      if (q == 0) {                  // C/D: row=(lane>>4)*4+reg, col=lane&15
        const int col = w * 128 + j * 16 + lo16;
        z_lds[0][col] = acc[0];      // batch 0 (row 0)
        z_lds[1][col] = acc[1];      // batch 1 (row 1)
      }
    }

    // prefetch next step's x fragments (drain under the h@R loop)
    {
      const int sn = (s + 1 < TT) ? s + 1 : s;
      load_a(xb, dir ? (TT - 1 - sn) : sn, q, av, afr);
    }

    // deferred h store from previous step (drains under the h@R loop)
    if (s > 0) hsp[(size_t)tx_prev * HH] = (_Float16)h_prev;

    __syncthreads();                 // xproj z_lds visible

    // ---- h @ R (fp32 VALU), thread owns cols {col0,col0+1} for both batches ----
    float a00 = z_lds[0][col0], a01 = z_lds[0][col0 + 1];
    float a10 = z_lds[1][col0], a11 = z_lds[1][col0 + 1];
    const float* rp = rec + col0;
#pragma unroll 16
    for (int k = 0; k < HH; ++k) {
      floatx2 rv = *reinterpret_cast<const floatx2*>(rp + (size_t)k * G4);
      floatx2 hv = *reinterpret_cast<const floatx2*>(&h_lds[k * 2]);  // broadcast
      a00 += hv[0] * rv[0]; a01 += hv[0] * rv[1];
      a10 += hv[1] * rv[0]; a11 += hv[1] * rv[1];
    }
    *reinterpret_cast<floatx2*>(&z_lds[0][col0]) = floatx2{a00, a01};
    *reinterpret_cast<floatx2*>(&z_lds[1][col0]) = floatx2{a10, a11};
    __syncthreads();

    // ---- gates (thread = (batch=half_id, h-index=l)); order i,f,g,o ----
    const float zi = z_lds[half_id][l] + bi;
    const float zf = z_lds[half_id][256 + l] + bf;
    const float zg = z_lds[half_id][512 + l] + bg;
    const float zo = z_lds[half_id][768 + l] + bo;
    c_state = sigm(zf) * c_state + sigm(zi) * tanh_f(zg);
    const float hval = sigm(zo) * tanh_f(c_state);
    h_lds[l * 2 + half_id] = hval;
    h_prev = hval; tx_prev = tx;
    __syncthreads();                 // h_lds/z_lds safe for next iteration
  }
  hsp[(size_t)tx_prev * HH] = (_Float16)h_prev;
}

// ---------------- attention: one block per batch ----------------

__global__ __launch_bounds__(256) void attn_kernel(const _Float16* __restrict__ hseq,
                                                   const float* __restrict__ att_w,
                                                   float* __restrict__ out) {
  const int b = blockIdx.x;
  const int tid = threadIdx.x;
  const int w = tid >> 6, lane = tid & 63;
  __shared__ float sc[TT];
  __shared__ float red[8];
  const _Float16* __restrict__ hf = hseq + (size_t)b * (TT * HH);
  const _Float16* __restrict__ hb = hseq + (size_t)(BB + b) * (TT * HH);

  const int h0 = lane * 4;
  const float aw0 = att_w[h0], aw1 = att_w[h0 + 1], aw2 = att_w[h0 + 2], aw3 = att_w[h0 + 3];

  // scores s_t = sum_h att_w[h] * tanh(hf+hb)
  for (int t = w; t < TT; t += 4) {
    half4_t f4 = *reinterpret_cast<const half4_t*>(hf + (size_t)t * HH + h0);
    half4_t b4 = *reinterpret_cast<const half4_t*>(hb + (size_t)t * HH + h0);
    float s = aw0 * tanh_f((float)f4[0] + (float)b4[0])
            + aw1 * tanh_f((float)f4[1] + (float)b4[1])
            + aw2 * tanh_f((float)f4[2] + (float)b4[2])
            + aw3 * tanh_f((float)f4[3] + (float)b4[3]);
#pragma unroll
    for (int off = 32; off >= 1; off >>= 1) s += __shfl_xor(s, off);
    if (lane == 0) sc[t] = s;
  }
  __syncthreads();

  // softmax over t
  float m = -1e30f;
  for (int i = tid; i < TT; i += 256) m = fmaxf(m, sc[i]);
#pragma unroll
  for (int off = 32; off >= 1; off >>= 1) m = fmaxf(m, __shfl_xor(m, off));
  if (lane == 0) red[w] = m;
  __syncthreads();
  m = fmaxf(fmaxf(red[0], red[1]), fmaxf(red[2], red[3]));

  float ssum = 0.f;
  for (int i = tid; i < TT; i += 256) {
    float e = __expf(sc[i] - m);
    sc[i] = e;
    ssum += e;
  }
#pragma unroll
  for (int off = 32; off >= 1; off >>= 1) ssum += __shfl_xor(ssum, off);
  if (lane == 0) red[4 + w] = ssum;
  __syncthreads();
  const float inv = 1.f / (red[4] + red[5] + red[6] + red[7]);

  // r[h] = sum_t a_t * (hf+hb)[t][h]; out = tanh(r)
  float r = 0.f;
  const _Float16* pf = hf + tid;
  const _Float16* pb = hb + tid;
  for (int t = 0; t < TT; ++t)
    r += sc[t] * ((float)pf[(size_t)t * HH] + (float)pb[(size_t)t * HH]);
  out[b * HH + tid] = tanh_f(r * inv);
}

// ---------------- launch ----------------

extern "C" void kernel_launch(void* const* d_in, const int* in_sizes, int n_in,
                              void* d_out, int out_size, void* d_ws, size_t ws_size,
                              hipStream_t stream) {
  const float* x     = (const float*)d_in[0];
  const float* k_fwd = (const float*)d_in[1];
  const float* r_fwd = (const float*)d_in[2];
  const float* b_fwd = (const float*)d_in[3];
  const float* k_bwd = (const float*)d_in[4];
  const float* r_bwd = (const float*)d_in[5];
  const float* b_bwd = (const float*)d_in[6];
  const float* att_w = (const float*)d_in[7];
  float* out = (float*)d_out;

  // workspace: kT (0.5 MB) + hseq fp16 (134 MB) = ~134.7 MB total
  const size_t kT_bytes = (size_t)2 * G4 * DD * sizeof(_Float16);        // 524,288
  char* ws = (char*)d_ws;
  _Float16* kT   = (_Float16*)ws;
  _Float16* hseq = (_Float16*)(ws + kT_bytes);

  hipLaunchKernelGGL(cvt_w_kernel, dim3(1024), dim3(256), 0, stream, k_fwd, k_bwd, kT);
  hipLaunchKernelGGL(lstm_rec_kernel, dim3(64), dim3(512), 0, stream,
                     x, r_fwd, r_bwd, b_fwd, b_bwd, kT, hseq);
  hipLaunchKernelGGL(attn_kernel, dim3(64), dim3(256), 0, stream, hseq, att_w, out);
}

// Round 4
// 12949.146 us; speedup vs baseline: 2.5370x; 2.5370x over previous
//
#include <hip/hip_runtime.h>
#include <cstdint>
#include <cstddef>

#define BBATCH 64
#define TT 2048
#define DD 128
#define HH 256
#define G4 1024

typedef _Float16 half4_t __attribute__((ext_vector_type(4)));
typedef _Float16 half8_t __attribute__((ext_vector_type(8)));
typedef float floatx4 __attribute__((ext_vector_type(4)));

__device__ __forceinline__ float sigm(float x) { return 1.f / (1.f + __expf(-x)); }
__device__ __forceinline__ float tanh_f(float x) { return 1.f - 2.f / (1.f + __expf(2.f * x)); }

__device__ __forceinline__ half8_t cvt8(float4 a, float4 b) {
  half8_t v;
  v[0] = (_Float16)a.x; v[1] = (_Float16)a.y; v[2] = (_Float16)a.z; v[3] = (_Float16)a.w;
  v[4] = (_Float16)b.x; v[5] = (_Float16)b.y; v[6] = (_Float16)b.z; v[7] = (_Float16)b.w;
  return v;
}

// ---------------- prep: RT[dir][n][k<256] = R[k][n] fp16 ; KT[dir][n][k<128] = K[k][n] fp16 ----
__global__ void prep_kernel(const float* __restrict__ rf, const float* __restrict__ rb,
                            const float* __restrict__ kf, const float* __restrict__ kb,
                            _Float16* __restrict__ RT, _Float16* __restrict__ KT) {
  int idx = blockIdx.x * 256 + threadIdx.x;     // 0 .. 786431
  if (idx < 2 * G4 * HH) {
    int dir = idx >> 18, k = (idx >> 10) & 255, n = idx & 1023;
    const float* src = dir ? rb : rf;
    RT[((size_t)(dir * G4 + n)) * HH + k] = (_Float16)src[(size_t)k * G4 + n];
  } else {
    int i2 = idx - 2 * G4 * HH;
    int dir = i2 >> 17, k = (i2 >> 10) & 127, n = i2 & 1023;
    const float* src = dir ? kb : kf;
    KT[((size_t)(dir * G4 + n)) * DD + k] = (_Float16)src[(size_t)k * G4 + n];
  }
}

// ---------------- recurrence: 32 blocks = 4 splits x (2 dirs x 4 batch-groups), 256 thr ----------
// Group g = dir*4+bg owns 16 batches; its 1024 cols split 4-ways (gate-aligned 64-h slices).
// Block (split,g): wave w owns h-sub [split*64+w*16, +16) -> 4 accumulator tiles = gates i,f,g,o.
// B-frags (R^T,K^T fp16) persistent in VGPRs. h exchanged per step via global (h_ex == hseq)
// with agent-scope release/acquire + flag counters: ONE increment per wave (lane 0 only!),
// 16 waves per group per step. No __syncthreads in the loop.

__global__ __launch_bounds__(256, 1) void lstm_rec_kernel(
    const float* __restrict__ x,
    const float* __restrict__ bias_f, const float* __restrict__ bias_b,
    const _Float16* __restrict__ RT, const _Float16* __restrict__ KT,
    _Float16* __restrict__ h_ex, int* __restrict__ flags) {
  const int bid = blockIdx.x;            // split*8 + g  (g = dir*4+bg)
  const int split = bid >> 3;
  const int g = bid & 7;
  const int dir = g >> 2;
  const int bg = g & 3;
  const int tid = threadIdx.x;
  const int w = tid >> 6, lane = tid & 63;
  const int lo16 = lane & 15, q = lane >> 4;

  const float* __restrict__ bias = dir ? bias_b : bias_f;

  // persistent B-fragments: B[k][n], lane holds k=q*8+j, n=lo16 -> contiguous in RT[n][k]
  half8_t bR[4][8], bK[4][4];
  float bgate[4];
#pragma unroll
  for (int gate = 0; gate < 4; ++gate) {
    const int col = gate * 256 + split * 64 + w * 16 + lo16;
    const _Float16* bp = RT + (size_t)(dir * G4 + col) * HH + q * 8;
#pragma unroll
    for (int kk = 0; kk < 8; ++kk) bR[gate][kk] = *reinterpret_cast<const half8_t*>(bp + kk * 32);
    const _Float16* kp = KT + (size_t)(dir * G4 + col) * DD + q * 8;
#pragma unroll
    for (int kx = 0; kx < 4; ++kx) bK[gate][kx] = *reinterpret_cast<const half8_t*>(kp + kx * 32);
    bgate[gate] = bias[col];
  }

  // x row for this lane's batch (A-operand row m = lo16)
  const float* __restrict__ xrow = x + ((size_t)(bg * 16 + lo16) * TT) * DD;
  _Float16* __restrict__ hex_g = h_ex + (size_t)g * TT * (16 * HH);
  int* __restrict__ flagg = flags + g * TT;

  float c[4] = {0.f, 0.f, 0.f, 0.f};

  // prefetch x fragments for s=0
  int tx = dir ? TT - 1 : 0;
  float4 xr[8];
  {
    const float* xp = xrow + (size_t)tx * DD + q * 8;
#pragma unroll
    for (int kx = 0; kx < 4; ++kx) {
      xr[2 * kx]     = *reinterpret_cast<const float4*>(xp + kx * 32);
      xr[2 * kx + 1] = *reinterpret_cast<const float4*>(xp + kx * 32 + 4);
    }
  }
  half8_t ax[4];
#pragma unroll
  for (int kx = 0; kx < 4; ++kx) ax[kx] = cvt8(xr[2 * kx], xr[2 * kx + 1]);

  for (int s = 0; s < TT; ++s) {
    tx = dir ? (TT - 1 - s) : s;

    floatx4 acc[4];
#pragma unroll
    for (int gate = 0; gate < 4; ++gate) acc[gate] = floatx4{0.f, 0.f, 0.f, 0.f};

    // xproj MFMAs (independent of h) — issue before the flag wait
#pragma unroll
    for (int kx = 0; kx < 4; ++kx)
#pragma unroll
      for (int gate = 0; gate < 4; ++gate)
        acc[gate] = __builtin_amdgcn_mfma_f32_16x16x32_f16(ax[kx], bK[gate][kx], acc[gate], 0, 0, 0);

    // prefetch next step's x (raw; converted after the heavy phase)
    {
      const int sn = (s + 1 < TT) ? s + 1 : s;
      const int txn = dir ? (TT - 1 - sn) : sn;
      const float* xp = xrow + (size_t)txn * DD + q * 8;
#pragma unroll
      for (int kx = 0; kx < 4; ++kx) {
        xr[2 * kx]     = *reinterpret_cast<const float4*>(xp + kx * 32);
        xr[2 * kx + 1] = *reinterpret_cast<const float4*>(xp + kx * 32 + 4);
      }
    }

    if (s > 0) {
      // wait for all 16 waves of this group to have published h_{s-1}
      while (__hip_atomic_load(&flagg[s - 1], __ATOMIC_RELAXED, __HIP_MEMORY_SCOPE_AGENT) < 16) {
        __builtin_amdgcn_s_sleep(1);
      }
      __builtin_amdgcn_fence(__ATOMIC_ACQUIRE, "agent");

      const int txp = dir ? tx + 1 : tx - 1;
      const _Float16* hp = hex_g + (size_t)txp * (16 * HH) + lo16 * HH + q * 8;
      half8_t ah[8];
#pragma unroll
      for (int kk = 0; kk < 8; ++kk) ah[kk] = *reinterpret_cast<const half8_t*>(hp + kk * 32);
#pragma unroll
      for (int kk = 0; kk < 8; ++kk)
#pragma unroll
        for (int gate = 0; gate < 4; ++gate)
          acc[gate] = __builtin_amdgcn_mfma_f32_16x16x32_f16(ah[kk], bR[gate][kk], acc[gate], 0, 0, 0);
    }

    // gates fully in-register: lane holds (batch=q*4+r, h=split*64+w*16+lo16) for r=0..3
    _Float16* hout = hex_g + (size_t)tx * (16 * HH) + split * 64 + w * 16 + lo16;
#pragma unroll
    for (int r = 0; r < 4; ++r) {
      const float zi = acc[0][r] + bgate[0];
      const float zf = acc[1][r] + bgate[1];
      const float zg = acc[2][r] + bgate[2];
      const float zo = acc[3][r] + bgate[3];
      c[r] = sigm(zf) * c[r] + sigm(zi) * tanh_f(zg);
      const float hv = sigm(zo) * tanh_f(c[r]);
      hout[(q * 4 + r) * HH] = (_Float16)hv;
    }

    __builtin_amdgcn_fence(__ATOMIC_RELEASE, "agent");
    if (lane == 0) {
      // ONE increment per wave — 16 waves per group total. (Per-lane add was the
      // round-3 race: each wave bumped the flag by 64, readers proceeded after
      // the first wave published.)
      __hip_atomic_fetch_add(&flagg[s], 1, __ATOMIC_RELAXED, __HIP_MEMORY_SCOPE_AGENT);
    }

    // convert prefetched x for next step
#pragma unroll
    for (int kx = 0; kx < 4; ++kx) ax[kx] = cvt8(xr[2 * kx], xr[2 * kx + 1]);
  }
}

// ---------------- attention: one block per batch; h_ex layout [g][t][b16][h] ----------------

__global__ __launch_bounds__(256) void attn_kernel(const _Float16* __restrict__ h_ex,
                                                   const float* __restrict__ att_w,
                                                   float* __restrict__ out) {
  const int b = blockIdx.x;
  const int bg = b >> 4, b16 = b & 15;
  const int tid = threadIdx.x;
  const int w = tid >> 6, lane = tid & 63;
  __shared__ float sc[TT];
  __shared__ float red[8];
  const size_t ST = 16 * HH;                       // per-t stride in halfs
  const _Float16* __restrict__ hf = h_ex + (size_t)bg * TT * ST + b16 * HH;
  const _Float16* __restrict__ hb = h_ex + (size_t)(4 + bg) * TT * ST + b16 * HH;

  const int h0 = lane * 4;
  const float aw0 = att_w[h0], aw1 = att_w[h0 + 1], aw2 = att_w[h0 + 2], aw3 = att_w[h0 + 3];

  for (int t = w; t < TT; t += 4) {
    half4_t f4 = *reinterpret_cast<const half4_t*>(hf + (size_t)t * ST + h0);
    half4_t b4 = *reinterpret_cast<const half4_t*>(hb + (size_t)t * ST + h0);
    float s = aw0 * tanh_f((float)f4[0] + (float)b4[0])
            + aw1 * tanh_f((float)f4[1] + (float)b4[1])
            + aw2 * tanh_f((float)f4[2] + (float)b4[2])
            + aw3 * tanh_f((float)f4[3] + (float)b4[3]);
#pragma unroll
    for (int off = 32; off >= 1; off >>= 1) s += __shfl_xor(s, off);
    if (lane == 0) sc[t] = s;
  }
  __syncthreads();

  float m = -1e30f;
  for (int i = tid; i < TT; i += 256) m = fmaxf(m, sc[i]);
#pragma unroll
  for (int off = 32; off >= 1; off >>= 1) m = fmaxf(m, __shfl_xor(m, off));
  if (lane == 0) red[w] = m;
  __syncthreads();
  m = fmaxf(fmaxf(red[0], red[1]), fmaxf(red[2], red[3]));

  float ssum = 0.f;
  for (int i = tid; i < TT; i += 256) {
    float e = __expf(sc[i] - m);
    sc[i] = e;
    ssum += e;
  }
#pragma unroll
  for (int off = 32; off >= 1; off >>= 1) ssum += __shfl_xor(ssum, off);
  if (lane == 0) red[4 + w] = ssum;
  __syncthreads();
  const float inv = 1.f / (red[4] + red[5] + red[6] + red[7]);

  float r = 0.f;
  const _Float16* pf = hf + tid;
  const _Float16* pb = hb + tid;
  for (int t = 0; t < TT; ++t)
    r += sc[t] * ((float)pf[(size_t)t * ST] + (float)pb[(size_t)t * ST]);
  out[b * HH + tid] = tanh_f(r * inv);
}

// ---------------- launch ----------------

extern "C" void kernel_launch(void* const* d_in, const int* in_sizes, int n_in,
                              void* d_out, int out_size, void* d_ws, size_t ws_size,
                              hipStream_t stream) {
  const float* x     = (const float*)d_in[0];
  const float* k_fwd = (const float*)d_in[1];
  const float* r_fwd = (const float*)d_in[2];
  const float* b_fwd = (const float*)d_in[3];
  const float* k_bwd = (const float*)d_in[4];
  const float* r_bwd = (const float*)d_in[5];
  const float* b_bwd = (const float*)d_in[6];
  const float* att_w = (const float*)d_in[7];
  float* out = (float*)d_out;

  // ws: RT 1 MB + KT 0.5 MB + flags 64 KB + h_ex 134 MB  (~135.7 MB total)
  const size_t RT_bytes   = (size_t)2 * G4 * HH * sizeof(_Float16);
  const size_t KT_bytes   = (size_t)2 * G4 * DD * sizeof(_Float16);
  const size_t flag_bytes = (size_t)8 * TT * sizeof(int);
  char* ws = (char*)d_ws;
  _Float16* RT    = (_Float16*)ws;
  _Float16* KT    = (_Float16*)(ws + RT_bytes);
  int*      flags = (int*)(ws + RT_bytes + KT_bytes);
  _Float16* h_ex  = (_Float16*)(ws + RT_bytes + KT_bytes + flag_bytes);

  hipMemsetAsync(flags, 0, flag_bytes, stream);
  hipLaunchKernelGGL(prep_kernel, dim3(3072), dim3(256), 0, stream,
                     r_fwd, r_bwd, k_fwd, k_bwd, RT, KT);
  hipLaunchKernelGGL(lstm_rec_kernel, dim3(32), dim3(256), 0, stream,
                     x, b_fwd, b_bwd, RT, KT, h_ex, flags);
  hipLaunchKernelGGL(attn_kernel, dim3(64), dim3(256), 0, stream, h_ex, att_w, out);
}

// Round 5
// 8458.967 us; speedup vs baseline: 3.8837x; 1.5308x over previous
//
#include <hip/hip_runtime.h>
#include <cstdint>
#include <cstddef>

#define TT 2048
#define DD 128
#define HH 256
#define G4 1024

typedef _Float16 half4_t __attribute__((ext_vector_type(4)));
typedef _Float16 half8_t __attribute__((ext_vector_type(8)));
typedef float floatx4 __attribute__((ext_vector_type(4)));

union H4U64 { uint64_t u; half4_t h; };
union H8U64x2 { uint64_t u[2]; half8_t h; };

__device__ __forceinline__ float sigm(float x) { return 1.f / (1.f + __expf(-x)); }
__device__ __forceinline__ float tanh_f(float x) { return 1.f - 2.f / (1.f + __expf(2.f * x)); }

__device__ __forceinline__ half8_t cvt8(float4 a, float4 b) {
  half8_t v;
  v[0] = (_Float16)a.x; v[1] = (_Float16)a.y; v[2] = (_Float16)a.z; v[3] = (_Float16)a.w;
  v[4] = (_Float16)b.x; v[5] = (_Float16)b.y; v[6] = (_Float16)b.z; v[7] = (_Float16)b.w;
  return v;
}

// ---------------- prep: RT[dir][n][k<256] = R[k][n] fp16 ; KT[dir][n][k<128] = K[k][n] fp16 ----
__global__ void prep_kernel(const float* __restrict__ rf, const float* __restrict__ rb,
                            const float* __restrict__ kf, const float* __restrict__ kb,
                            _Float16* __restrict__ RT, _Float16* __restrict__ KT) {
  int idx = blockIdx.x * 256 + threadIdx.x;     // 0 .. 786431
  if (idx < 2 * G4 * HH) {
    int dir = idx >> 18, k = (idx >> 10) & 255, n = idx & 1023;
    const float* src = dir ? rb : rf;
    RT[((size_t)(dir * G4 + n)) * HH + k] = (_Float16)src[(size_t)k * G4 + n];
  } else {
    int i2 = idx - 2 * G4 * HH;
    int dir = i2 >> 17, k = (i2 >> 10) & 127, n = i2 & 1023;
    const float* src = dir ? kb : kf;
    KT[((size_t)(dir * G4 + n)) * DD + k] = (_Float16)src[(size_t)k * G4 + n];
  }
}

// ---------------- recurrence ----------------
// 32 blocks = 4 splits x (2 dirs x 4 batch-groups g), 256 thr (4 waves).
// Wave w of block (split,g) owns h-slice split*64+w*16+lo16 for gates i,f,g,o (4 acc tiles).
// h exchange: NO fences (round-4's agent fences -> per-step L2 wb/inv was the 6 us/step).
// Instead per-op device-scoped atomics: ring[slot][g][kg][b][8halfs] written as 8-B scoped
// stores (after LDS transpose), gathered as 8-B scoped loads (straight to LLC, L2 untouched).
// Order: stores -> __syncthreads (vmcnt(0) drain) -> one flag add per BLOCK (threshold 4).

__global__ __launch_bounds__(256, 1) void lstm_rec_kernel(
    const float* __restrict__ x,
    const float* __restrict__ bias_f, const float* __restrict__ bias_b,
    const _Float16* __restrict__ RT, const _Float16* __restrict__ KT,
    uint64_t* __restrict__ ring, int* __restrict__ flags,
    _Float16* __restrict__ hseq) {
  const int bid = blockIdx.x;            // split*8 + g   (g = dir*4 + bg)
  const int split = bid >> 3;
  const int g = bid & 7;
  const int dir = g >> 2;
  const int bg = g & 3;
  const int tid = threadIdx.x;
  const int w = tid >> 6, lane = tid & 63;
  const int lo16 = lane & 15, q = lane >> 4;

  __shared__ _Float16 tile[2][64][16];   // [step parity][h_local][batch]

  const float* __restrict__ bias = dir ? bias_b : bias_f;

  // persistent B-fragments (k-contiguous in RT/KT rows) — same as round 4 (verified layout)
  half8_t bR[4][8], bK[4][4];
  float bgate[4];
#pragma unroll
  for (int gate = 0; gate < 4; ++gate) {
    const int col = gate * 256 + split * 64 + w * 16 + lo16;
    const _Float16* bp = RT + (size_t)(dir * G4 + col) * HH + q * 8;
#pragma unroll
    for (int kk = 0; kk < 8; ++kk) bR[gate][kk] = *reinterpret_cast<const half8_t*>(bp + kk * 32);
    const _Float16* kp = KT + (size_t)(dir * G4 + col) * DD + q * 8;
#pragma unroll
    for (int kx = 0; kx < 4; ++kx) bK[gate][kx] = *reinterpret_cast<const half8_t*>(kp + kx * 32);
    bgate[gate] = bias[col];
  }

  // x row for this lane's batch (A-operand row m = lo16)
  const float* __restrict__ xrow = x + ((size_t)(bg * 16 + lo16) * TT) * DD;
  int* __restrict__ flagg = flags + g * TT;

  // transpose/publish role of this thread
  const int kgl  = tid >> 5;            // 0..7 local k-group (8 h each)
  const int tb   = (tid >> 1) & 15;     // batch
  const int part = tid & 1;             // low/high 4 halfs
  const int kg_global = split * 8 + kgl;
  const int hofs = split * 64 + kgl * 8 + part * 4;

  float c[4] = {0.f, 0.f, 0.f, 0.f};

  // prefetch x fragments for s=0
  int tx = dir ? TT - 1 : 0;
  float4 xr[8];
  {
    const float* xp = xrow + (size_t)tx * DD + q * 8;
#pragma unroll
    for (int kx = 0; kx < 4; ++kx) {
      xr[2 * kx]     = *reinterpret_cast<const float4*>(xp + kx * 32);
      xr[2 * kx + 1] = *reinterpret_cast<const float4*>(xp + kx * 32 + 4);
    }
  }
  half8_t ax[4];
#pragma unroll
  for (int kx = 0; kx < 4; ++kx) ax[kx] = cvt8(xr[2 * kx], xr[2 * kx + 1]);

  for (int s = 0; s < TT; ++s) {
    tx = dir ? (TT - 1 - s) : s;

    floatx4 acc[4];
#pragma unroll
    for (int gate = 0; gate < 4; ++gate) acc[gate] = floatx4{0.f, 0.f, 0.f, 0.f};

    // xproj MFMAs (independent of h) — before the flag wait
#pragma unroll
    for (int kx = 0; kx < 4; ++kx)
#pragma unroll
      for (int gate = 0; gate < 4; ++gate)
        acc[gate] = __builtin_amdgcn_mfma_f32_16x16x32_f16(ax[kx], bK[gate][kx], acc[gate], 0, 0, 0);

    // prefetch next step's x
    {
      const int sn = (s + 1 < TT) ? s + 1 : s;
      const int txn = dir ? (TT - 1 - sn) : sn;
      const float* xp = xrow + (size_t)txn * DD + q * 8;
#pragma unroll
      for (int kx = 0; kx < 4; ++kx) {
        xr[2 * kx]     = *reinterpret_cast<const float4*>(xp + kx * 32);
        xr[2 * kx + 1] = *reinterpret_cast<const float4*>(xp + kx * 32 + 4);
      }
    }

    if (s > 0) {
      while (__hip_atomic_load(&flagg[s - 1], __ATOMIC_RELAXED, __HIP_MEMORY_SCOPE_AGENT) < 4) {
        __builtin_amdgcn_s_sleep(1);
      }
      asm volatile("" ::: "memory");   // compiler barrier: keep gather after the spin

      // gather h_{s-1} A-frags: 16 x 8-B device-scoped loads (LLC, bypass L1/L2)
      const uint64_t* rs = ring + ((size_t)(((s - 1) & 3) * 8 + g)) * 1024;
      half8_t ah[8];
#pragma unroll
      for (int kk = 0; kk < 8; ++kk) {
        H8U64x2 u;
        const uint64_t* p = rs + (size_t)(((kk * 4 + q) * 16 + lo16) * 2);
        u.u[0] = __hip_atomic_load((uint64_t*)(p),     __ATOMIC_RELAXED, __HIP_MEMORY_SCOPE_AGENT);
        u.u[1] = __hip_atomic_load((uint64_t*)(p + 1), __ATOMIC_RELAXED, __HIP_MEMORY_SCOPE_AGENT);
        ah[kk] = u.h;
      }
#pragma unroll
      for (int kk = 0; kk < 8; ++kk)
#pragma unroll
        for (int gate = 0; gate < 4; ++gate)
          acc[gate] = __builtin_amdgcn_mfma_f32_16x16x32_f16(ah[kk], bR[gate][kk], acc[gate], 0, 0, 0);
    }

    // gates: lane holds (batch=q*4+r, h_idx=split*64+w*16+lo16); order i,f,g,o
    const int par = s & 1;
    {
      half4_t hv4;
#pragma unroll
      for (int r = 0; r < 4; ++r) {
        const float zi = acc[0][r] + bgate[0];
        const float zf = acc[1][r] + bgate[1];
        const float zg = acc[2][r] + bgate[2];
        const float zo = acc[3][r] + bgate[3];
        c[r] = sigm(zf) * c[r] + sigm(zi) * tanh_f(zg);
        hv4[r] = (_Float16)(sigm(zo) * tanh_f(c[r]));
      }
      // one 8-B LDS write: batches q*4..q*4+3 at h_local = w*16+lo16
      *reinterpret_cast<half4_t*>(&tile[par][w * 16 + lo16][q * 4]) = hv4;
    }
    __syncthreads();                     // tile[par] visible block-wide

    // transpose-publish: 4 halfs k-contiguous for batch tb
    {
      H4U64 val;
#pragma unroll
      for (int j = 0; j < 4; ++j) val.h[j] = tile[par][kgl * 8 + part * 4 + j][tb];
      uint64_t* rp = ring + ((size_t)((s & 3) * 8 + g)) * 1024 + (kg_global * 16 + tb) * 2 + part;
      __hip_atomic_store(rp, val.u, __ATOMIC_RELAXED, __HIP_MEMORY_SCOPE_AGENT);
      // plain store to hseq [g][t][b16][h] for the attention kernel
      *reinterpret_cast<uint64_t*>(hseq + ((size_t)g * TT + tx) * (16 * HH) + (size_t)tb * HH + hofs) = val.u;
    }
    __syncthreads();                     // implicit vmcnt(0): all ring stores drained
    if (tid == 0) {
      __hip_atomic_fetch_add(&flagg[s], 1, __ATOMIC_RELAXED, __HIP_MEMORY_SCOPE_AGENT);
    }

    // convert prefetched x for next step
#pragma unroll
    for (int kx = 0; kx < 4; ++kx) ax[kx] = cvt8(xr[2 * kx], xr[2 * kx + 1]);
  }
}

// ---------------- attention: one block per batch; hseq layout [g][t][b16][h] ----------------

__global__ __launch_bounds__(256) void attn_kernel(const _Float16* __restrict__ h_ex,
                                                   const float* __restrict__ att_w,
                                                   float* __restrict__ out) {
  const int b = blockIdx.x;
  const int bg = b >> 4, b16 = b & 15;
  const int tid = threadIdx.x;
  const int w = tid >> 6, lane = tid & 63;
  __shared__ float sc[TT];
  __shared__ float red[8];
  const size_t ST = 16 * HH;
  const _Float16* __restrict__ hf = h_ex + (size_t)bg * TT * ST + b16 * HH;
  const _Float16* __restrict__ hb = h_ex + (size_t)(4 + bg) * TT * ST + b16 * HH;

  const int h0 = lane * 4;
  const float aw0 = att_w[h0], aw1 = att_w[h0 + 1], aw2 = att_w[h0 + 2], aw3 = att_w[h0 + 3];

  for (int t = w; t < TT; t += 4) {
    half4_t f4 = *reinterpret_cast<const half4_t*>(hf + (size_t)t * ST + h0);
    half4_t b4 = *reinterpret_cast<const half4_t*>(hb + (size_t)t * ST + h0);
    float s = aw0 * tanh_f((float)f4[0] + (float)b4[0])
            + aw1 * tanh_f((float)f4[1] + (float)b4[1])
            + aw2 * tanh_f((float)f4[2] + (float)b4[2])
            + aw3 * tanh_f((float)f4[3] + (float)b4[3]);
#pragma unroll
    for (int off = 32; off >= 1; off >>= 1) s += __shfl_xor(s, off);
    if (lane == 0) sc[t] = s;
  }
  __syncthreads();

  float m = -1e30f;
  for (int i = tid; i < TT; i += 256) m = fmaxf(m, sc[i]);
#pragma unroll
  for (int off = 32; off >= 1; off >>= 1) m = fmaxf(m, __shfl_xor(m, off));
  if (lane == 0) red[w] = m;
  __syncthreads();
  m = fmaxf(fmaxf(red[0], red[1]), fmaxf(red[2], red[3]));

  float ssum = 0.f;
  for (int i = tid; i < TT; i += 256) {
    float e = __expf(sc[i] - m);
    sc[i] = e;
    ssum += e;
  }
#pragma unroll
  for (int off = 32; off >= 1; off >>= 1) ssum += __shfl_xor(ssum, off);
  if (lane == 0) red[4 + w] = ssum;
  __syncthreads();
  const float inv = 1.f / (red[4] + red[5] + red[6] + red[7]);

  float r = 0.f;
  const _Float16* pf = hf + tid;
  const _Float16* pb = hb + tid;
  for (int t = 0; t < TT; ++t)
    r += sc[t] * ((float)pf[(size_t)t * ST] + (float)pb[(size_t)t * ST]);
  out[b * HH + tid] = tanh_f(r * inv);
}

// ---------------- launch ----------------

extern "C" void kernel_launch(void* const* d_in, const int* in_sizes, int n_in,
                              void* d_out, int out_size, void* d_ws, size_t ws_size,
                              hipStream_t stream) {
  const float* x     = (const float*)d_in[0];
  const float* k_fwd = (const float*)d_in[1];
  const float* r_fwd = (const float*)d_in[2];
  const float* b_fwd = (const float*)d_in[3];
  const float* k_bwd = (const float*)d_in[4];
  const float* r_bwd = (const float*)d_in[5];
  const float* b_bwd = (const float*)d_in[6];
  const float* att_w = (const float*)d_in[7];
  float* out = (float*)d_out;

  // ws: RT 1 MB + KT 0.5 MB + flags 64 KB + ring 256 KB + hseq 128 MB  (~135.5 MB)
  const size_t RT_bytes   = (size_t)2 * G4 * HH * sizeof(_Float16);
  const size_t KT_bytes   = (size_t)2 * G4 * DD * sizeof(_Float16);
  const size_t flag_bytes = (size_t)8 * TT * sizeof(int);
  const size_t ring_bytes = (size_t)4 * 8 * 1024 * sizeof(uint64_t);   // 4 slots x 8 g x 1024 u64
  char* ws = (char*)d_ws;
  _Float16* RT    = (_Float16*)ws;
  _Float16* KT    = (_Float16*)(ws + RT_bytes);
  int*      flags = (int*)(ws + RT_bytes + KT_bytes);
  uint64_t* ring  = (uint64_t*)(ws + RT_bytes + KT_bytes + flag_bytes);
  _Float16* hseq  = (_Float16*)(ws + RT_bytes + KT_bytes + flag_bytes + ring_bytes);

  hipMemsetAsync(flags, 0, flag_bytes, stream);
  hipLaunchKernelGGL(prep_kernel, dim3(3072), dim3(256), 0, stream,
                     r_fwd, r_bwd, k_fwd, k_bwd, RT, KT);
  hipLaunchKernelGGL(lstm_rec_kernel, dim3(32), dim3(256), 0, stream,
                     x, b_fwd, b_bwd, RT, KT, ring, flags, hseq);
  hipLaunchKernelGGL(attn_kernel, dim3(64), dim3(256), 0, stream, hseq, att_w, out);
}

// Round 6
// 7602.169 us; speedup vs baseline: 4.3214x; 1.1127x over previous
//
#include <hip/hip_runtime.h>
#include <cstdint>
#include <cstddef>

#define TT 2048
#define DD 128
#define HH 256
#define G4 1024

typedef _Float16 half4_t __attribute__((ext_vector_type(4)));
typedef _Float16 half8_t __attribute__((ext_vector_type(8)));
typedef float floatx4 __attribute__((ext_vector_type(4)));

union H4U64 { uint64_t u; half4_t h; };
union H8U64x2 { uint64_t u[2]; half8_t h; };

__device__ __forceinline__ float sigm(float x) { return 1.f / (1.f + __expf(-x)); }
__device__ __forceinline__ float tanh_f(float x) { return 1.f - 2.f / (1.f + __expf(2.f * x)); }

__device__ __forceinline__ half8_t cvt8(float4 a, float4 b) {
  half8_t v;
  v[0] = (_Float16)a.x; v[1] = (_Float16)a.y; v[2] = (_Float16)a.z; v[3] = (_Float16)a.w;
  v[4] = (_Float16)b.x; v[5] = (_Float16)b.y; v[6] = (_Float16)b.z; v[7] = (_Float16)b.w;
  return v;
}

// ---------------- prep: RT[dir][n][k<256] = R[k][n] fp16 ; KT[dir][n][k<128] = K[k][n] fp16 ----
__global__ void prep_kernel(const float* __restrict__ rf, const float* __restrict__ rb,
                            const float* __restrict__ kf, const float* __restrict__ kb,
                            _Float16* __restrict__ RT, _Float16* __restrict__ KT) {
  int idx = blockIdx.x * 256 + threadIdx.x;     // 0 .. 786431
  if (idx < 2 * G4 * HH) {
    int dir = idx >> 18, k = (idx >> 10) & 255, n = idx & 1023;
    const float* src = dir ? rb : rf;
    RT[((size_t)(dir * G4 + n)) * HH + k] = (_Float16)src[(size_t)k * G4 + n];
  } else {
    int i2 = idx - 2 * G4 * HH;
    int dir = i2 >> 17, k = (i2 >> 10) & 127, n = i2 & 1023;
    const float* src = dir ? kb : kf;
    KT[((size_t)(dir * G4 + n)) * DD + k] = (_Float16)src[(size_t)k * G4 + n];
  }
}

// ---------------- recurrence ----------------
// 32 blocks = 4 splits x (2 dirs x 4 batch-groups g), 256 thr (4 waves).
// Round-6 protocol (all agent scope, placement-independent):
//   per-WAVE monotonic flags (stores, no RMW): wave drains its own vmcnt(0) (inline asm,
//   no block barrier) then stores flag = s+1. hseq HBM store issued AFTER the flag.
//   Consumer: all 64 lanes load flags[lane&15], exit on __all(>=s); gather 16x8B LLC
//   loads first, xproj MFMAs overlap the gather flight, then R-MFMAs.
//   One __syncthreads per step (LDS transpose, parity double-buffered tile).

__global__ __launch_bounds__(256, 1) void lstm_rec_kernel(
    const float* __restrict__ x,
    const float* __restrict__ bias_f, const float* __restrict__ bias_b,
    const _Float16* __restrict__ RT, const _Float16* __restrict__ KT,
    uint64_t* __restrict__ ring, int* __restrict__ flags,
    _Float16* __restrict__ hseq) {
  const int bid = blockIdx.x;            // split*8 + g   (g = dir*4 + bg)
  const int split = bid >> 3;
  const int g = bid & 7;
  const int dir = g >> 2;
  const int bg = g & 3;
  const int tid = threadIdx.x;
  const int w = tid >> 6, lane = tid & 63;
  const int lo16 = lane & 15, q = lane >> 4;

  __shared__ _Float16 tile[2][64][20];   // [parity][h_local][batch padded 16->20: 8B-aligned rows, conflict-free]

  const float* __restrict__ bias = dir ? bias_b : bias_f;

  // persistent B-fragments (k-contiguous in RT/KT rows) — verified layout (rounds 4/5)
  half8_t bR[4][8], bK[4][4];
  float bgate[4];
#pragma unroll
  for (int gate = 0; gate < 4; ++gate) {
    const int col = gate * 256 + split * 64 + w * 16 + lo16;
    const _Float16* bp = RT + (size_t)(dir * G4 + col) * HH + q * 8;
#pragma unroll
    for (int kk = 0; kk < 8; ++kk) bR[gate][kk] = *reinterpret_cast<const half8_t*>(bp + kk * 32);
    const _Float16* kp = KT + (size_t)(dir * G4 + col) * DD + q * 8;
#pragma unroll
    for (int kx = 0; kx < 4; ++kx) bK[gate][kx] = *reinterpret_cast<const half8_t*>(kp + kx * 32);
    bgate[gate] = bias[col];
  }

  // x row for this lane's batch (A-operand row m = lo16)
  const float* __restrict__ xrow = x + ((size_t)(bg * 16 + lo16) * TT) * DD;
  int* __restrict__ flagG = flags + g * 32;   // 16 wave-flags per group (128B-padded groups)

  // transpose/publish role of this thread
  const int kgl  = tid >> 5;            // 0..7 local k-group (8 h each)
  const int tb   = (tid >> 1) & 15;     // batch
  const int part = tid & 1;             // low/high 4 halfs
  const int kg_global = split * 8 + kgl;
  const int hofs = split * 64 + kgl * 8 + part * 4;

  float c[4] = {0.f, 0.f, 0.f, 0.f};

  // prefetch x fragments for s=0
  int tx = dir ? TT - 1 : 0;
  float4 xr[8];
  {
    const float* xp = xrow + (size_t)tx * DD + q * 8;
#pragma unroll
    for (int kx = 0; kx < 4; ++kx) {
      xr[2 * kx]     = *reinterpret_cast<const float4*>(xp + kx * 32);
      xr[2 * kx + 1] = *reinterpret_cast<const float4*>(xp + kx * 32 + 4);
    }
  }
  half8_t ax[4];
#pragma unroll
  for (int kx = 0; kx < 4; ++kx) ax[kx] = cvt8(xr[2 * kx], xr[2 * kx + 1]);

  for (int s = 0; s < TT; ++s) {
    tx = dir ? (TT - 1 - s) : s;

    // prefetch next step's x (drains in background during spin/compute)
    {
      const int sn = (s + 1 < TT) ? s + 1 : s;
      const int txn = dir ? (TT - 1 - sn) : sn;
      const float* xp = xrow + (size_t)txn * DD + q * 8;
#pragma unroll
      for (int kx = 0; kx < 4; ++kx) {
        xr[2 * kx]     = *reinterpret_cast<const float4*>(xp + kx * 32);
        xr[2 * kx + 1] = *reinterpret_cast<const float4*>(xp + kx * 32 + 4);
      }
    }

    floatx4 acc[4];
#pragma unroll
    for (int gate = 0; gate < 4; ++gate) acc[gate] = floatx4{0.f, 0.f, 0.f, 0.f};

    half8_t ah[8];
    if (s > 0) {
      // wait for all 16 waves of the group to have published h_{s-1}
      while (true) {
        int v = __hip_atomic_load(&flagG[lane & 15], __ATOMIC_RELAXED, __HIP_MEMORY_SCOPE_AGENT);
        if (__all(v >= s)) break;
        __builtin_amdgcn_s_sleep(1);
      }
      asm volatile("" ::: "memory");   // keep the gather after the spin

      // issue the 16 x 8-B LLC gather first...
      const uint64_t* rs = ring + ((size_t)(((s - 1) & 3) * 8 + g)) * 1024;
#pragma unroll
      for (int kk = 0; kk < 8; ++kk) {
        H8U64x2 u;
        const uint64_t* p = rs + (size_t)(((kk * 4 + q) * 16 + lo16) * 2);
        u.u[0] = __hip_atomic_load((uint64_t*)(p),     __ATOMIC_RELAXED, __HIP_MEMORY_SCOPE_AGENT);
        u.u[1] = __hip_atomic_load((uint64_t*)(p + 1), __ATOMIC_RELAXED, __HIP_MEMORY_SCOPE_AGENT);
        ah[kk] = u.h;
      }
    }

    // ...xproj MFMAs execute while the gather is in flight
#pragma unroll
    for (int kx = 0; kx < 4; ++kx)
#pragma unroll
      for (int gate = 0; gate < 4; ++gate)
        acc[gate] = __builtin_amdgcn_mfma_f32_16x16x32_f16(ax[kx], bK[gate][kx], acc[gate], 0, 0, 0);

    if (s > 0) {
#pragma unroll
      for (int kk = 0; kk < 8; ++kk)
#pragma unroll
        for (int gate = 0; gate < 4; ++gate)
          acc[gate] = __builtin_amdgcn_mfma_f32_16x16x32_f16(ah[kk], bR[gate][kk], acc[gate], 0, 0, 0);
    }

    // gates: lane holds (batch=q*4+r, h_idx=split*64+w*16+lo16); order i,f,g,o
    const int par = s & 1;
    {
      half4_t hv4;
#pragma unroll
      for (int r = 0; r < 4; ++r) {
        const float zi = acc[0][r] + bgate[0];
        const float zf = acc[1][r] + bgate[1];
        const float zg = acc[2][r] + bgate[2];
        const float zo = acc[3][r] + bgate[3];
        c[r] = sigm(zf) * c[r] + sigm(zi) * tanh_f(zg);
        hv4[r] = (_Float16)(sigm(zo) * tanh_f(c[r]));
      }
      *reinterpret_cast<half4_t*>(&tile[par][w * 16 + lo16][q * 4]) = hv4;
    }
    __syncthreads();                     // tile[par] visible block-wide (only barrier per step)

    // transpose-publish: 4 halfs k-contiguous for batch tb
    {
      H4U64 val;
#pragma unroll
      for (int j = 0; j < 4; ++j) val.h[j] = tile[par][kgl * 8 + part * 4 + j][tb];
      uint64_t* rp = ring + ((size_t)((s & 3) * 8 + g)) * 1024 + (kg_global * 16 + tb) * 2 + part;
      __hip_atomic_store(rp, val.u, __ATOMIC_RELAXED, __HIP_MEMORY_SCOPE_AGENT);

      // per-WAVE drain + flag store (no barrier, no RMW)
      asm volatile("s_waitcnt vmcnt(0)" ::: "memory");
      if ((tid & 63) == 0) {
        __hip_atomic_store(&flagG[split * 4 + w], s + 1, __ATOMIC_RELAXED, __HIP_MEMORY_SCOPE_AGENT);
      }

      // hseq HBM store AFTER the flag — drains lazily under next step's compute
      *reinterpret_cast<uint64_t*>(hseq + ((size_t)g * TT + tx) * (16 * HH) + (size_t)tb * HH + hofs) = val.u;
    }

    // convert prefetched x for next step
#pragma unroll
    for (int kx = 0; kx < 4; ++kx) ax[kx] = cvt8(xr[2 * kx], xr[2 * kx + 1]);
  }
}

// ---------------- attention: one block per batch; hseq layout [g][t][b16][h] ----------------

__global__ __launch_bounds__(256) void attn_kernel(const _Float16* __restrict__ h_ex,
                                                   const float* __restrict__ att_w,
                                                   float* __restrict__ out) {
  const int b = blockIdx.x;
  const int bg = b >> 4, b16 = b & 15;
  const int tid = threadIdx.x;
  const int w = tid >> 6, lane = tid & 63;
  __shared__ float sc[TT];
  __shared__ float red[8];
  const size_t ST = 16 * HH;
  const _Float16* __restrict__ hf = h_ex + (size_t)bg * TT * ST + b16 * HH;
  const _Float16* __restrict__ hb = h_ex + (size_t)(4 + bg) * TT * ST + b16 * HH;

  const int h0 = lane * 4;
  const float aw0 = att_w[h0], aw1 = att_w[h0 + 1], aw2 = att_w[h0 + 2], aw3 = att_w[h0 + 3];

  for (int t = w; t < TT; t += 4) {
    half4_t f4 = *reinterpret_cast<const half4_t*>(hf + (size_t)t * ST + h0);
    half4_t b4 = *reinterpret_cast<const half4_t*>(hb + (size_t)t * ST + h0);
    float s = aw0 * tanh_f((float)f4[0] + (float)b4[0])
            + aw1 * tanh_f((float)f4[1] + (float)b4[1])
            + aw2 * tanh_f((float)f4[2] + (float)b4[2])
            + aw3 * tanh_f((float)f4[3] + (float)b4[3]);
#pragma unroll
    for (int off = 32; off >= 1; off >>= 1) s += __shfl_xor(s, off);
    if (lane == 0) sc[t] = s;
  }
  __syncthreads();

  float m = -1e30f;
  for (int i = tid; i < TT; i += 256) m = fmaxf(m, sc[i]);
#pragma unroll
  for (int off = 32; off >= 1; off >>= 1) m = fmaxf(m, __shfl_xor(m, off));
  if (lane == 0) red[w] = m;
  __syncthreads();
  m = fmaxf(fmaxf(red[0], red[1]), fmaxf(red[2], red[3]));

  float ssum = 0.f;
  for (int i = tid; i < TT; i += 256) {
    float e = __expf(sc[i] - m);
    sc[i] = e;
    ssum += e;
  }
#pragma unroll
  for (int off = 32; off >= 1; off >>= 1) ssum += __shfl_xor(ssum, off);
  if (lane == 0) red[4 + w] = ssum;
  __syncthreads();
  const float inv = 1.f / (red[4] + red[5] + red[6] + red[7]);

  float r = 0.f;
  const _Float16* pf = hf + tid;
  const _Float16* pb = hb + tid;
  for (int t = 0; t < TT; ++t)
    r += sc[t] * ((float)pf[(size_t)t * ST] + (float)pb[(size_t)t * ST]);
  out[b * HH + tid] = tanh_f(r * inv);
}

// ---------------- launch ----------------

extern "C" void kernel_launch(void* const* d_in, const int* in_sizes, int n_in,
                              void* d_out, int out_size, void* d_ws, size_t ws_size,
                              hipStream_t stream) {
  const float* x     = (const float*)d_in[0];
  const float* k_fwd = (const float*)d_in[1];
  const float* r_fwd = (const float*)d_in[2];
  const float* b_fwd = (const float*)d_in[3];
  const float* k_bwd = (const float*)d_in[4];
  const float* r_bwd = (const float*)d_in[5];
  const float* b_bwd = (const float*)d_in[6];
  const float* att_w = (const float*)d_in[7];
  float* out = (float*)d_out;

  // ws: RT 1 MB + KT 0.5 MB + flags 1 KB + ring 256 KB + hseq 128 MB  (~135.5 MB)
  const size_t RT_bytes   = (size_t)2 * G4 * HH * sizeof(_Float16);
  const size_t KT_bytes   = (size_t)2 * G4 * DD * sizeof(_Float16);
  const size_t flag_bytes = (size_t)8 * 32 * sizeof(int);              // 8 groups x 16 wave-flags (padded)
  const size_t ring_bytes = (size_t)4 * 8 * 1024 * sizeof(uint64_t);   // 4 slots x 8 g x 1024 u64
  char* ws = (char*)d_ws;
  _Float16* RT    = (_Float16*)ws;
  _Float16* KT    = (_Float16*)(ws + RT_bytes);
  int*      flags = (int*)(ws + RT_bytes + KT_bytes);
  uint64_t* ring  = (uint64_t*)(ws + RT_bytes + KT_bytes + flag_bytes);
  _Float16* hseq  = (_Float16*)(ws + RT_bytes + KT_bytes + flag_bytes + ring_bytes);

  hipMemsetAsync(flags, 0, flag_bytes, stream);
  hipLaunchKernelGGL(prep_kernel, dim3(3072), dim3(256), 0, stream,
                     r_fwd, r_bwd, k_fwd, k_bwd, RT, KT);
  hipLaunchKernelGGL(lstm_rec_kernel, dim3(32), dim3(256), 0, stream,
                     x, b_fwd, b_bwd, RT, KT, ring, flags, hseq);
  hipLaunchKernelGGL(attn_kernel, dim3(64), dim3(256), 0, stream, hseq, att_w, out);
}